// Round 11
// baseline (483.910 us; speedup 1.0000x reference)
//
#include <hip/hip_runtime.h>
#include <hip/hip_bf16.h>

typedef __hip_bfloat16 bf16;
typedef float f32x4 __attribute__((ext_vector_type(4)));
typedef short bf16x8 __attribute__((ext_vector_type(8)));
typedef short short4v __attribute__((ext_vector_type(4)));
typedef unsigned int u32;

#define NTOK 100352   // 32*56*56 tokens = 2048 windows * 49
#define CC 192
#define HIDN 768

__device__ __forceinline__ float b2f(unsigned short u) {
    union { unsigned int u32v; float f; } x; x.u32v = ((unsigned int)u) << 16; return x.f;
}
__device__ __forceinline__ unsigned short f2b(float f) {
    union { float f; unsigned int u; } x; x.f = f;
    unsigned int r = x.u + 0x7FFF + ((x.u >> 16) & 1);
    return (unsigned short)(r >> 16);
}
// tanh-form gelu via hardware exp: |err vs exact erf-gelu| <= ~3e-4, far under harness threshold
__device__ __forceinline__ float gelu_f(float x) {
    float x3 = x * x * x;
    float y2 = 1.5957691216f * (x + 0.044715f * x3);   // 2 * 0.7978845608 * (...)
    float e = __expf(y2);
    float th = 1.0f - 2.0f / (e + 1.0f);
    return 0.5f * x * (1.0f + th);
}

typedef __attribute__((address_space(1))) const unsigned char gas_u8;
typedef __attribute__((address_space(3))) unsigned char las_u8;
__device__ __forceinline__ void gload_lds16(const void* g, void* l) {
    __builtin_amdgcn_global_load_lds((gas_u8*)g, (las_u8*)l, 16, 0, 0);
}

// ---------------- weight prep: fp32 src [R][C] -> bf16 dst[c*R + r] (c < Cpad; zero-pad c >= C) ----------------
__global__ void transpose_k(const float* __restrict__ src, bf16* __restrict__ dst,
                            int R, int C, int Cpad) {
    int idx = blockIdx.x * 256 + threadIdx.x;
    if (idx >= R * Cpad) return;
    int c = idx / R, r = idx % R;
    dst[idx] = (c < C) ? __float2bfloat16(src[(size_t)r * C + c]) : __float2bfloat16(0.0f);
}

// ---------------- biasmask table: [cls][head][mt][nt][lane][reg] f32, acc-frag layout. ----------------
__global__ void bm_k(const float* __restrict__ btab, float* __restrict__ bm) {
    int idx = blockIdx.x * 256 + threadIdx.x;           // 4*6*16*256 = 98304
    if (idx >= 98304) return;
    int reg = idx & 3, lane = (idx >> 2) & 63, tile = (idx >> 8) & 15;
    int rest = idx >> 12, h = rest % 6, cls = rest / 6;
    int mt = tile >> 2, nt = tile & 3;
    int kk = mt * 16 + (lane >> 4) * 4 + reg;
    int q  = nt * 16 + (lane & 15);
    float v;
    if (kk >= 49 || q >= 49) v = -1e9f;
    else {
        int i1 = q / 7, j1 = q % 7, i2 = kk / 7, j2 = kk % 7;
        v = btab[((i1 - i2 + 6) * 13 + (j1 - j2 + 6)) * 6 + h];
        int hb7 = cls >> 1, wb7 = cls & 1;
        int r1 = (hb7 ? (i1 < 4 ? 1 : 2) : 0) * 3 + (wb7 ? (j1 < 4 ? 1 : 2) : 0);
        int r2 = (hb7 ? (i2 < 4 ? 1 : 2) : 0) * 3 + (wb7 ? (j2 < 4 ? 1 : 2) : 0);
        if (r1 != r2) v -= 100.0f;
    }
    bm[idx] = v;
}

// ---------------- LayerNorm (wave per token) -> bf16 rows. ----------------
template<bool GATHER>
__global__ __launch_bounds__(256) void ln_k(const float* __restrict__ src,
                                            const float* __restrict__ gamma,
                                            const float* __restrict__ beta,
                                            bf16* __restrict__ dst) {
    int wave = threadIdx.x >> 6, lane = threadIdx.x & 63;
    int t = blockIdx.x * 4 + wave;           // output token index
    size_t srow;
    if (GATHER) {
        int w = t / 49, n = t % 49;
        int b = w >> 6, wl = w & 63, hb = wl >> 3, wb = wl & 7;
        int i = n / 7, j = n % 7;
        int sh = hb * 7 + i + 3; if (sh >= 56) sh -= 56;   // roll(-3): src=(dst+3)%56
        int sw = wb * 7 + j + 3; if (sw >= 56) sw -= 56;
        srow = ((size_t)(b * 56 + sh) * 56 + sw) * CC;
    } else {
        srow = (size_t)t * CC;
    }
    float v[4];
    int c = lane * 4;
    float sum = 0.f, sq = 0.f;
    if (lane < 48) {
        f32x4 d = *(const f32x4*)(src + srow + c);
        #pragma unroll
        for (int q = 0; q < 4; ++q) { v[q] = d[q]; sum += v[q]; sq += v[q] * v[q]; }
    }
    #pragma unroll
    for (int off = 1; off < 64; off <<= 1) { sum += __shfl_xor(sum, off); sq += __shfl_xor(sq, off); }
    float mu = sum * (1.0f / 192.0f);
    float var = sq * (1.0f / 192.0f) - mu * mu;
    float rstd = rsqrtf(var + 1e-5f);
    if (lane < 48) {
        f32x4 gg = *(const f32x4*)(gamma + c);
        f32x4 bb = *(const f32x4*)(beta + c);
        short4v o;
        #pragma unroll
        for (int q = 0; q < 4; ++q) {
            float val = (v[q] - mu) * rstd * gg[q] + bb[q];
            o[q] = (short)f2b(val);
        }
        *(short4v*)(dst + (size_t)t * CC + c) = o;
    }
}

// ---------------- Tiled MFMA GEMM. X staged in LDS (BM=128, BK=64, dbuf, swizzled);
// W (weights) read per-frag DIRECT FROM GLOBAL (L2-resident; XCD-chunked swizzle keeps panels hot).
// OPERAND-SWAPPED MFMA: mfma(Wfrag, Xfrag) -> lane l&15 owns one output ROW; regs = 4 consecutive
// output cols -> vectorized epilogue (b64 bf16 / b128 f32 stores), scatter index once per m-frag.
// WIDE=1: BN=128, wave 64x64 (acc[4][4]); WIDE=0: BN=64, wave 64x32 (acc[4][2]).
// EPI 0: +bias -> bf16 outb; EPI 1: +bias, reverse+roll(+3,+3) scatter, outf = xres + val;
// EPI 2: +bias, gelu -> bf16; EPI 3: +bias + yin -> fp32 outf;
// EPI 4: +bias -> head-planar bf16 [(col>>5)*NTOK + m]*32 + (col&31).
// NR = real N (cols >= NR skipped; WT zero-padded to N rows).
template<int EPI, int WIDE>
__global__ __launch_bounds__(256) void gemm_t(
    const bf16* __restrict__ X, const bf16* __restrict__ WT,
    const float* __restrict__ bias, int K, int N, int NR,
    bf16* __restrict__ outb, float* __restrict__ outf,
    const float* __restrict__ xres, const float* __restrict__ yin, int mbase)
{
    constexpr int BN = WIDE ? 128 : 64;
    constexpr int NF = WIDE ? 4 : 2;      // n-frags per wave
    __shared__ bf16 As[2][128 * 64];      // X tile only: 16 KiB per buffer
    const int tid = threadIdx.x;
    const int w = tid >> 6, lane = tid & 63;
    const int w0 = w & 1, w1 = w >> 1;
    const int nOff = WIDE ? w0 * 64 : w0 * 32;

    // bijective XCD-chunked swizzle (all grids here have nwg % 8 == 0)
    const u32 nwg = gridDim.x * gridDim.y;
    u32 bid = blockIdx.y * gridDim.x + blockIdx.x;
    bid = (bid & 7) * (nwg >> 3) + (bid >> 3);
    const int tn0 = (bid % gridDim.x) * BN;
    const int tm0 = (bid / gridDim.x) * 128;

    const int r16 = lane & 15, g8 = (lane >> 4) * 8;

    // X staging addresses (hoisted)
    const bf16* gA[4];
    #pragma unroll
    for (int j = 0; j < 4; ++j) {
        int c = (w * 4 + j) * 64 + lane;
        int l = c ^ ((c >> 3) & 7);          // inverse swizzle on source
        gA[j] = X + (size_t)(tm0 + (c >> 3)) * K + (l & 7) * 8;
    }
    auto stage = [&](int buf, int kk) {
        #pragma unroll
        for (int j = 0; j < 4; ++j)
            gload_lds16(gA[j] + kk, (char*)&As[buf][0] + (size_t)(w * 4 + j) * 1024);
    };

    // W frag pointers (A-operand), direct global
    const bf16* gW[NF];
    #pragma unroll
    for (int n = 0; n < NF; ++n)
        gW[n] = WT + (size_t)(tn0 + nOff + n * 16 + r16) * K + g8;

    f32x4 acc[4][NF] = {};
    const int ntile = K >> 6;
    stage(0, 0);
    __syncthreads();
    for (int t = 0; t < ntile; ++t) {
        int buf = t & 1;
        if (t + 1 < ntile) stage(buf ^ 1, (t + 1) << 6);
        const char* ab = (const char*)&As[buf][0];
        #pragma unroll
        for (int k32 = 0; k32 < 2; ++k32) {
            int kg = (t << 6) + k32 * 32;         // global k for W frags
            int kcolb = k32 * 64 + g8 * 2;        // LDS byte col for X frags
            bf16x8 xf[4], wf[NF];
            #pragma unroll
            for (int m = 0; m < 4; ++m) {
                int row = w1 * 64 + m * 16 + r16;
                int byte = row * 128 + kcolb;
                xf[m] = *(const bf16x8*)(ab + (byte ^ ((row & 7) << 4)));
            }
            #pragma unroll
            for (int n = 0; n < NF; ++n)
                wf[n] = *(const bf16x8*)(gW[n] + kg);
            #pragma unroll
            for (int m = 0; m < 4; ++m)
                #pragma unroll
                for (int n = 0; n < NF; ++n)
                    acc[m][n] = __builtin_amdgcn_mfma_f32_16x16x32_bf16(wf[n], xf[m], acc[m][n], 0, 0, 0);
        }
        __syncthreads();
    }

    // Epilogue: lane owns row mm = ...+ (lane&15); regs are 4 consecutive cols at q4.
    const int q4 = (lane >> 4) * 4;
    #pragma unroll
    for (int mt = 0; mt < 4; ++mt) {
        int mm = tm0 + w1 * 64 + mt * 16 + r16;
        size_t rowbase;
        if (EPI == 1) {
            int gm = mbase + mm;
            int ww = gm / 49, nn = gm % 49;
            int b_ = ww >> 6, wl = ww & 63, hb = wl >> 3, wb = wl & 7;
            int i = nn / 7, j = nn % 7;
            int oh = hb * 7 + i + 3; if (oh >= 56) oh -= 56;   // roll(+3)
            int ow = wb * 7 + j + 3; if (ow >= 56) ow -= 56;
            rowbase = ((size_t)(b_ * 56 + oh) * 56 + ow) * CC;
        } else {
            rowbase = (size_t)mm * NR;
        }
        #pragma unroll
        for (int nt = 0; nt < NF; ++nt) {
            int col = tn0 + nOff + nt * 16 + q4;
            if (col >= NR) continue;
            f32x4 bv = *(const f32x4*)(bias + col);
            f32x4 v;
            #pragma unroll
            for (int r = 0; r < 4; ++r) v[r] = acc[mt][nt][r] + bv[r];
            if (EPI == 0) {
                short4v o;
                #pragma unroll
                for (int r = 0; r < 4; ++r) o[r] = (short)f2b(v[r]);
                *(short4v*)(outb + rowbase + col) = o;
            } else if (EPI == 1) {
                f32x4 xr = *(const f32x4*)(xres + rowbase + col);
                #pragma unroll
                for (int r = 0; r < 4; ++r) v[r] += xr[r];
                *(f32x4*)(outf + rowbase + col) = v;
            } else if (EPI == 2) {
                short4v o;
                #pragma unroll
                for (int r = 0; r < 4; ++r) o[r] = (short)f2b(gelu_f(v[r]));
                *(short4v*)(outb + rowbase + col) = o;
            } else if (EPI == 3) {
                f32x4 yv = *(const f32x4*)(yin + rowbase + col);
                #pragma unroll
                for (int r = 0; r < 4; ++r) v[r] += yv[r];
                *(f32x4*)(outf + rowbase + col) = v;
            } else {
                size_t ob = ((size_t)(col >> 5) * NTOK + mm) * 32 + (col & 31);
                short4v o;
                #pragma unroll
                for (int r = 0; r < 4; ++r) o[r] = (short)f2b(v[r]);
                *(short4v*)(outb + ob) = o;
            }
        }
    }
}

// ---------------- MFMA attention: block = 1 window (384 thr = 6 waves, one per head). ----------------
__global__ __launch_bounds__(384) void attn_m(const bf16* __restrict__ qkv,
                                              const float* __restrict__ bm,
                                              bf16* __restrict__ out)
{
    __shared__ char Pl[6][8192];    // P[q][kk] bf16, byte = q*128+kk*2 ^ ((q&7)<<4)
    __shared__ char Vt[6][4096];    // V^T[d][kk] bf16, byte = d*128+kk*2 ^ ((d&7)<<4)
    const int w = blockIdx.x;
    const int h = threadIdx.x >> 6, l = threadIdx.x & 63;
    const int w49 = w * 49;
    const int wl = w & 63;
    const int cls = (((wl >> 3) == 7) ? 2 : 0) + (((wl & 7) == 7) ? 1 : 0);
    const int hi8 = (l >> 4) * 8, lo = l & 15;

    // ---- stage V^T (zero-pad kk>=49) ----
    {
        const bf16* vbase = qkv + ((size_t)(12 + h) * NTOK + w49) * 32;
        #pragma unroll
        for (int it = 0; it < 4; ++it) {
            int c = it * 64 + l;                 // [0,256): kk=c>>2, 8-elem group c&3
            int kk = c >> 2, off = (c & 3) * 8;
            bf16x8 v = {};
            if (c < 196) v = *(const bf16x8*)(vbase + kk * 32 + off);
            #pragma unroll
            for (int j = 0; j < 8; ++j) {
                int d = off + j;
                int byte = (d * 128 + kk * 2) ^ ((d & 7) << 4);
                *(bf16*)(&Vt[h][0] + byte) = ((const bf16*)&v)[j];
            }
        }
    }

    // ---- QK^T: D[kk][q], 4x4 tiles of 16x16, K=32 ----
    const bf16* qb = qkv + ((size_t)h * NTOK + w49) * 32 + hi8;
    const bf16* kb = qkv + ((size_t)(6 + h) * NTOK + w49) * 32 + hi8;
    bf16x8 af[4], bf_[4];
    #pragma unroll
    for (int mt = 0; mt < 4; ++mt) af[mt] = *(const bf16x8*)(kb + (size_t)(mt * 16 + lo) * 32);
    #pragma unroll
    for (int ntt = 0; ntt < 4; ++ntt) bf_[ntt] = *(const bf16x8*)(qb + (size_t)(ntt * 16 + lo) * 32);
    f32x4 acc[4][4] = {};
    #pragma unroll
    for (int mt = 0; mt < 4; ++mt)
        #pragma unroll
        for (int ntt = 0; ntt < 4; ++ntt)
            acc[mt][ntt] = __builtin_amdgcn_mfma_f32_16x16x32_bf16(af[mt], bf_[ntt], acc[mt][ntt], 0, 0, 0);

    // ---- scale + biasmask ----
    const float scale = 0.17677669529663689f;   // 32^-0.5
    const float* bmb = bm + ((size_t)(cls * 6 + h) << 4) * 256;
    #pragma unroll
    for (int mt = 0; mt < 4; ++mt)
        #pragma unroll
        for (int ntt = 0; ntt < 4; ++ntt) {
            f32x4 bmv = *(const f32x4*)(bmb + (mt * 4 + ntt) * 256 + l * 4);
            #pragma unroll
            for (int r = 0; r < 4; ++r) acc[mt][ntt][r] = acc[mt][ntt][r] * scale + bmv[r];
        }

    // ---- softmax over kk (rows) per q (col): in-reg over mt,r then shfl over l>>4 ----
    float inv[4], mx[4];
    #pragma unroll
    for (int ntt = 0; ntt < 4; ++ntt) {
        float m_ = -1e30f;
        #pragma unroll
        for (int mt = 0; mt < 4; ++mt)
            #pragma unroll
            for (int r = 0; r < 4; ++r) m_ = fmaxf(m_, acc[mt][ntt][r]);
        m_ = fmaxf(m_, __shfl_xor(m_, 16));
        m_ = fmaxf(m_, __shfl_xor(m_, 32));
        mx[ntt] = m_;
    }
    #pragma unroll
    for (int ntt = 0; ntt < 4; ++ntt) {
        float s_ = 0.f;
        #pragma unroll
        for (int mt = 0; mt < 4; ++mt)
            #pragma unroll
            for (int r = 0; r < 4; ++r) {
                float e = __expf(acc[mt][ntt][r] - mx[ntt]);
                acc[mt][ntt][r] = e;
                s_ += e;
            }
        s_ += __shfl_xor(s_, 16);
        s_ += __shfl_xor(s_, 32);
        inv[ntt] = 1.0f / s_;
    }

    // ---- P -> LDS (packed b32 writes; kk pairs adjacent) ----
    #pragma unroll
    for (int mt = 0; mt < 4; ++mt)
        #pragma unroll
        for (int ntt = 0; ntt < 4; ++ntt)
            #pragma unroll
            for (int rp = 0; rp < 4; rp += 2) {
                u32 pk = (u32)f2b(acc[mt][ntt][rp]) | ((u32)f2b(acc[mt][ntt][rp + 1]) << 16);
                int kk = mt * 16 + (l >> 4) * 4 + rp;
                int q  = ntt * 16 + lo;
                int byte = (q * 128 + kk * 2) ^ ((q & 7) << 4);
                *(u32*)(&Pl[h][0] + byte) = pk;
            }

    // ---- PV: O[q][d] = P[q][kk] @ V^T rows, K=64 (2 steps) ----
    f32x4 o[4][2] = {};
    #pragma unroll
    for (int ks = 0; ks < 2; ++ks) {
        int kb_ = (ks * 32 + hi8) * 2;
        bf16x8 pa[4], vb[2];
        #pragma unroll
        for (int qt = 0; qt < 4; ++qt) {
            int row = qt * 16 + lo;
            pa[qt] = *(const bf16x8*)(&Pl[h][0] + ((row * 128 + kb_) ^ ((row & 7) << 4)));
        }
        #pragma unroll
        for (int dt = 0; dt < 2; ++dt) {
            int row = dt * 16 + lo;
            vb[dt] = *(const bf16x8*)(&Vt[h][0] + ((row * 128 + kb_) ^ ((row & 7) << 4)));
        }
        #pragma unroll
        for (int qt = 0; qt < 4; ++qt)
            #pragma unroll
            for (int dt = 0; dt < 2; ++dt)
                o[qt][dt] = __builtin_amdgcn_mfma_f32_16x16x32_bf16(pa[qt], vb[dt], o[qt][dt], 0, 0, 0);
    }

    // ---- scale by 1/sum (shfl broadcast) and store ----
    #pragma unroll
    for (int qt = 0; qt < 4; ++qt)
        #pragma unroll
        for (int r = 0; r < 4; ++r) {
            int qrow = (l >> 4) * 4 + r;
            float iv = __shfl(inv[qt], qrow);
            int q = qt * 16 + qrow;
            if (q < 49) {
                size_t ob = (size_t)(w49 + q) * CC + h * 32 + lo;
                out[ob]      = __float2bfloat16(o[qt][0][r] * iv);
                out[ob + 16] = __float2bfloat16(o[qt][1][r] * iv);
            }
        }
}

// ---------------- launch ----------------
extern "C" void kernel_launch(void* const* d_in, const int* in_sizes, int n_in,
                              void* d_out, int out_size, void* d_ws, size_t ws_size,
                              hipStream_t stream) {
    const float* x      = (const float*)d_in[0];
    const float* n1g    = (const float*)d_in[1];
    const float* n1b    = (const float*)d_in[2];
    const float* qkv_w  = (const float*)d_in[3];
    const float* qkv_b  = (const float*)d_in[4];
    const float* proj_w = (const float*)d_in[5];
    const float* proj_b = (const float*)d_in[6];
    const float* btab   = (const float*)d_in[7];
    const float* n2g    = (const float*)d_in[8];
    const float* n2b    = (const float*)d_in[9];
    const float* fc1_w  = (const float*)d_in[10];
    const float* fc1_b  = (const float*)d_in[11];
    const float* fc2_w  = (const float*)d_in[12];
    const float* fc2_b  = (const float*)d_in[13];

    char* ws = (char*)d_ws;
    //  xw   [0, 38535168)            bf16 [100352][192]  (LN1 out; reused as LN2 out m)
    //  qkv  [38535168, 154140672)    bf16 head-planar [3][6][NTOK][32]
    //        (MLP phase: hid bf16 [100352][768] reuses [38535168, 192675840))
    //  att  [154140672, 192675840)   bf16 [100352][192]
    //  wt   [192675840, 193585152)   transposed bf16 weights (qkv padded to 640 rows)
    //  bm   [193585152, 193978368)   biasmask f32 [4][6][16][256]
    //  y (fp32) lives in d_out.
    const size_t XW_OFF  = 0;
    const size_t QKV_OFF = 38535168;
    const size_t ATT_OFF = 154140672;
    const size_t WT_OFF  = 192675840;
    const size_t BM_OFF  = 193585152;
    if (ws_size < 193978368ull) return;   // diagnostic: zeros signature (absmax ~5.59)

    bf16* xw   = (bf16*)(ws + XW_OFF);
    bf16* mbuf = (bf16*)(ws + XW_OFF);
    bf16* qkvb = (bf16*)(ws + QKV_OFF);
    bf16* attb = (bf16*)(ws + ATT_OFF);
    bf16* hidb = (bf16*)(ws + QKV_OFF);
    float* yf  = (float*)d_out;
    bf16* wt   = (bf16*)(ws + WT_OFF);
    float* bmt = (float*)(ws + BM_OFF);
    bf16* qkv_wT  = wt;                       // [640][192] (rows 576..639 zero)
    bf16* proj_wT = wt + 122880;              // [192][192]
    bf16* fc1_wT  = wt + 159744;              // [768][192]
    bf16* fc2_wT  = wt + 307200;              // [192][768]

    transpose_k<<<dim3(480), 256, 0, stream>>>(qkv_w, qkv_wT, 192, 576, 640);
    transpose_k<<<dim3(144), 256, 0, stream>>>(proj_w, proj_wT, 192, 192, 192);
    transpose_k<<<dim3(576), 256, 0, stream>>>(fc1_w, fc1_wT, 192, 768, 768);
    transpose_k<<<dim3(576), 256, 0, stream>>>(fc2_w, fc2_wT, 768, 192, 192);
    bm_k<<<dim3(384), 256, 0, stream>>>(btab, bmt);

    ln_k<true><<<NTOK / 4, 256, 0, stream>>>(x, n1g, n1b, xw);

    gemm_t<4, 1><<<dim3(5, 784), 256, 0, stream>>>(
        xw, qkv_wT, qkv_b, 192, 640, 576, qkvb, nullptr, nullptr, nullptr, 0);
    attn_m<<<dim3(2048), 384, 0, stream>>>(qkvb, bmt, attb);
    gemm_t<1, 0><<<dim3(3, 784), 256, 0, stream>>>(
        attb, proj_wT, proj_b, 192, 192, 192, nullptr, yf, x, nullptr, 0);

    ln_k<false><<<NTOK / 4, 256, 0, stream>>>(yf, n2g, n2b, mbuf);

    gemm_t<2, 1><<<dim3(6, 784), 256, 0, stream>>>(
        mbuf, fc1_wT, fc1_b, 192, 768, 768, hidb, nullptr, nullptr, nullptr, 0);
    gemm_t<3, 0><<<dim3(3, 784), 256, 0, stream>>>(
        hidb, fc2_wT, fc2_b, 768, 192, 192, nullptr, yf, nullptr, yf, 0);
}

// Round 12
// 396.355 us; speedup vs baseline: 1.2209x; 1.2209x over previous
//
#include <hip/hip_runtime.h>
#include <hip/hip_bf16.h>

typedef __hip_bfloat16 bf16;
typedef float f32x4 __attribute__((ext_vector_type(4)));
typedef short bf16x8 __attribute__((ext_vector_type(8)));
typedef short short4v __attribute__((ext_vector_type(4)));
typedef unsigned int u32;

#define NTOK 100352   // 32*56*56 tokens = 2048 windows * 49
#define CC 192
#define HIDN 768

__device__ __forceinline__ float b2f(unsigned short u) {
    union { unsigned int u32v; float f; } x; x.u32v = ((unsigned int)u) << 16; return x.f;
}
__device__ __forceinline__ unsigned short f2b(float f) {
    union { float f; unsigned int u; } x; x.f = f;
    unsigned int r = x.u + 0x7FFF + ((x.u >> 16) & 1);
    return (unsigned short)(r >> 16);
}
// tanh-form gelu via hardware exp: |err vs exact erf-gelu| <= ~3e-4 (validated R11, absmax unchanged)
__device__ __forceinline__ float gelu_f(float x) {
    float x3 = x * x * x;
    float y2 = 1.5957691216f * (x + 0.044715f * x3);
    float e = __expf(y2);
    float th = 1.0f - 2.0f / (e + 1.0f);
    return 0.5f * x * (1.0f + th);
}

typedef __attribute__((address_space(1))) const unsigned char gas_u8;
typedef __attribute__((address_space(3))) unsigned char las_u8;
__device__ __forceinline__ void gload_lds16(const void* g, void* l) {
    __builtin_amdgcn_global_load_lds((gas_u8*)g, (las_u8*)l, 16, 0, 0);
}

// ---------------- weight prep: fp32 src [R][C] -> bf16 dst[c*R + r] ----------------
__global__ void transpose_k(const float* __restrict__ src, bf16* __restrict__ dst, int R, int C) {
    int idx = blockIdx.x * 256 + threadIdx.x;
    if (idx >= R * C) return;
    int r = idx / C, c = idx % C;
    dst[(size_t)c * R + r] = __float2bfloat16(src[idx]);
}

// ---------------- biasmask table: [cls][head][mt][nt][lane][reg] f32, acc-frag layout. ----------------
__global__ void bm_k(const float* __restrict__ btab, float* __restrict__ bm) {
    int idx = blockIdx.x * 256 + threadIdx.x;           // 4*6*16*256 = 98304
    if (idx >= 98304) return;
    int reg = idx & 3, lane = (idx >> 2) & 63, tile = (idx >> 8) & 15;
    int rest = idx >> 12, h = rest % 6, cls = rest / 6;
    int mt = tile >> 2, nt = tile & 3;
    int kk = mt * 16 + (lane >> 4) * 4 + reg;
    int q  = nt * 16 + (lane & 15);
    float v;
    if (kk >= 49 || q >= 49) v = -1e9f;
    else {
        int i1 = q / 7, j1 = q % 7, i2 = kk / 7, j2 = kk % 7;
        v = btab[((i1 - i2 + 6) * 13 + (j1 - j2 + 6)) * 6 + h];
        int hb7 = cls >> 1, wb7 = cls & 1;
        int r1 = (hb7 ? (i1 < 4 ? 1 : 2) : 0) * 3 + (wb7 ? (j1 < 4 ? 1 : 2) : 0);
        int r2 = (hb7 ? (i2 < 4 ? 1 : 2) : 0) * 3 + (wb7 ? (j2 < 4 ? 1 : 2) : 0);
        if (r1 != r2) v -= 100.0f;
    }
    bm[idx] = v;
}

// ---------------- LayerNorm (wave per token) -> bf16 rows. ----------------
template<bool GATHER>
__global__ __launch_bounds__(256) void ln_k(const float* __restrict__ src,
                                            const float* __restrict__ gamma,
                                            const float* __restrict__ beta,
                                            bf16* __restrict__ dst) {
    int wave = threadIdx.x >> 6, lane = threadIdx.x & 63;
    int t = blockIdx.x * 4 + wave;           // output token index
    size_t srow;
    if (GATHER) {
        int w = t / 49, n = t % 49;
        int b = w >> 6, wl = w & 63, hb = wl >> 3, wb = wl & 7;
        int i = n / 7, j = n % 7;
        int sh = hb * 7 + i + 3; if (sh >= 56) sh -= 56;   // roll(-3): src=(dst+3)%56
        int sw = wb * 7 + j + 3; if (sw >= 56) sw -= 56;
        srow = ((size_t)(b * 56 + sh) * 56 + sw) * CC;
    } else {
        srow = (size_t)t * CC;
    }
    float v[4];
    int c = lane * 4;
    float sum = 0.f, sq = 0.f;
    if (lane < 48) {
        f32x4 d = *(const f32x4*)(src + srow + c);
        #pragma unroll
        for (int q = 0; q < 4; ++q) { v[q] = d[q]; sum += v[q]; sq += v[q] * v[q]; }
    }
    #pragma unroll
    for (int off = 1; off < 64; off <<= 1) { sum += __shfl_xor(sum, off); sq += __shfl_xor(sq, off); }
    float mu = sum * (1.0f / 192.0f);
    float var = sq * (1.0f / 192.0f) - mu * mu;
    float rstd = rsqrtf(var + 1e-5f);
    if (lane < 48) {
        f32x4 gg = *(const f32x4*)(gamma + c);
        f32x4 bb = *(const f32x4*)(beta + c);
        short4v o;
        #pragma unroll
        for (int q = 0; q < 4; ++q) {
            float val = (v[q] - mu) * rstd * gg[q] + bb[q];
            o[q] = (short)f2b(val);
        }
        *(short4v*)(dst + (size_t)t * CC + c) = o;
    }
}

// ======== shared epilogue (operand-swapped D-layout: lane&15 = output row within 16-frag,
// (lane>>4)*4 + reg = 4 consecutive output cols -> vector stores) ========
// EPI 1: +bias, reverse+roll(+3,+3) scatter, outf[dst] = xres[dst] + val (fp32)
// EPI 2: +bias, gelu -> bf16 outb
// EPI 3: +bias + yin(fp32) -> fp32 outf
// EPI 4: +bias -> head-planar bf16: [((col>>5)*NTOK + m)*32 + (col&31)]
template<int EPI>
__device__ __forceinline__ void epilogue(
    f32x4 (&acc)[4][2], int tm0, int tn0, int w0, int w1, int lane, int N,
    const float* __restrict__ bias, bf16* __restrict__ outb, float* __restrict__ outf,
    const float* __restrict__ xres, const float* __restrict__ yin)
{
    const int r16 = lane & 15, q4 = (lane >> 4) * 4;
    #pragma unroll
    for (int mt = 0; mt < 4; ++mt) {
        int mm = tm0 + w1 * 64 + mt * 16 + r16;
        size_t rowbase;
        if (EPI == 1) {
            int ww = mm / 49, nn = mm % 49;
            int b_ = ww >> 6, wl = ww & 63, hb = wl >> 3, wb = wl & 7;
            int i = nn / 7, j = nn % 7;
            int oh = hb * 7 + i + 3; if (oh >= 56) oh -= 56;   // roll(+3)
            int ow = wb * 7 + j + 3; if (ow >= 56) ow -= 56;
            rowbase = ((size_t)(b_ * 56 + oh) * 56 + ow) * CC;
        } else {
            rowbase = (size_t)mm * N;
        }
        #pragma unroll
        for (int nt = 0; nt < 2; ++nt) {
            int col = tn0 + w0 * 32 + nt * 16 + q4;
            f32x4 bv = *(const f32x4*)(bias + col);
            f32x4 v;
            #pragma unroll
            for (int r = 0; r < 4; ++r) v[r] = acc[mt][nt][r] + bv[r];
            if (EPI == 1) {
                f32x4 xr = *(const f32x4*)(xres + rowbase + col);
                #pragma unroll
                for (int r = 0; r < 4; ++r) v[r] += xr[r];
                *(f32x4*)(outf + rowbase + col) = v;
            } else if (EPI == 2) {
                short4v o;
                #pragma unroll
                for (int r = 0; r < 4; ++r) o[r] = (short)f2b(gelu_f(v[r]));
                *(short4v*)(outb + rowbase + col) = o;
            } else if (EPI == 3) {
                f32x4 yv = *(const f32x4*)(yin + rowbase + col);
                #pragma unroll
                for (int r = 0; r < 4; ++r) v[r] += yv[r];
                *(f32x4*)(outf + rowbase + col) = v;
            } else {
                size_t ob = ((size_t)(col >> 5) * NTOK + mm) * 32 + (col & 31);
                short4v o;
                #pragma unroll
                for (int r = 0; r < 4; ++r) o[r] = (short)f2b(v[r]);
                *(short4v*)(outb + ob) = o;
            }
        }
    }
}

// ---------------- SINGLE-SHOT GEMM for K<=192: stage ALL K-tiles (nt<=3) into LDS at once,
// ONE barrier, then uninterrupted MFMA stream (no dbuf, no per-tile sync).
// BM=128, BN=64, 4 waves 2x2, swizzled LDS (R9-validated layout), XCD-chunked block swizzle. ----------------
template<int EPI>
__global__ __launch_bounds__(256) void gemm_ss(
    const bf16* __restrict__ X, const bf16* __restrict__ WT,
    const float* __restrict__ bias, int K, int N,
    bf16* __restrict__ outb, float* __restrict__ outf,
    const float* __restrict__ xres, const float* __restrict__ yin)
{
    __shared__ bf16 As[3][128 * 64];   // 16 KiB per K-tile
    __shared__ bf16 Bs[3][64 * 64];    // 8 KiB per K-tile
    const int tid = threadIdx.x;
    const int w = tid >> 6, lane = tid & 63;
    const int w0 = w & 1, w1 = w >> 1;

    const u32 nwg = gridDim.x * gridDim.y;
    u32 bid = blockIdx.y * gridDim.x + blockIdx.x;
    bid = (bid & 7) * (nwg >> 3) + (bid >> 3);          // bijective (nwg%8==0)
    const int tn0 = (bid % gridDim.x) * 64;
    const int tm0 = (bid / gridDim.x) * 128;

    const int r16 = lane & 15, g8 = (lane >> 4) * 8;

    const bf16* gA[4];
    const bf16* gB[2];
    #pragma unroll
    for (int j = 0; j < 4; ++j) {
        int c = (w * 4 + j) * 64 + lane;
        int l = c ^ ((c >> 3) & 7);          // inverse swizzle on source
        gA[j] = X + (size_t)(tm0 + (c >> 3)) * K + (l & 7) * 8;
    }
    #pragma unroll
    for (int j = 0; j < 2; ++j) {
        int c = (w * 2 + j) * 64 + lane;
        int l = c ^ ((c >> 3) & 7);
        gB[j] = WT + (size_t)(tn0 + (c >> 3)) * K + (l & 7) * 8;
    }

    const int nt = K >> 6;                   // <= 3
    for (int t = 0; t < nt; ++t) {           // issue ALL stages back-to-back
        #pragma unroll
        for (int j = 0; j < 4; ++j)
            gload_lds16(gA[j] + (t << 6), (char*)&As[t][0] + (size_t)(w * 4 + j) * 1024);
        #pragma unroll
        for (int j = 0; j < 2; ++j)
            gload_lds16(gB[j] + (t << 6), (char*)&Bs[t][0] + (size_t)(w * 2 + j) * 1024);
    }
    __syncthreads();                          // the ONLY barrier

    f32x4 acc[4][2] = {};
    for (int t = 0; t < nt; ++t) {
        const char* ab = (const char*)&As[t][0];
        const char* bb_ = (const char*)&Bs[t][0];
        #pragma unroll
        for (int k32 = 0; k32 < 2; ++k32) {
            int kcolb = k32 * 64 + g8 * 2;
            bf16x8 xf[4], wf[2];
            #pragma unroll
            for (int m = 0; m < 4; ++m) {
                int row = w1 * 64 + m * 16 + r16;
                int byte = row * 128 + kcolb;
                xf[m] = *(const bf16x8*)(ab + (byte ^ ((row & 7) << 4)));
            }
            #pragma unroll
            for (int n = 0; n < 2; ++n) {
                int row = w0 * 32 + n * 16 + r16;
                int byte = row * 128 + kcolb;
                wf[n] = *(const bf16x8*)(bb_ + (byte ^ ((row & 7) << 4)));
            }
            #pragma unroll
            for (int m = 0; m < 4; ++m)
                #pragma unroll
                for (int n = 0; n < 2; ++n)
                    acc[m][n] = __builtin_amdgcn_mfma_f32_16x16x32_bf16(wf[n], xf[m], acc[m][n], 0, 0, 0);
        }
    }
    epilogue<EPI>(acc, tm0, tn0, w0, w1, lane, N, bias, outb, outf, xres, yin);
}

// ---------------- Double-buffered GEMM for large K (fc2, K=768). R9 structure + swapped
// operands + vector epilogue. ----------------
template<int EPI>
__global__ __launch_bounds__(256) void gemm_db(
    const bf16* __restrict__ X, const bf16* __restrict__ WT,
    const float* __restrict__ bias, int K, int N,
    bf16* __restrict__ outb, float* __restrict__ outf,
    const float* __restrict__ xres, const float* __restrict__ yin)
{
    __shared__ bf16 As[2][128 * 64];
    __shared__ bf16 Bs[2][64 * 64];
    const int tid = threadIdx.x;
    const int w = tid >> 6, lane = tid & 63;
    const int w0 = w & 1, w1 = w >> 1;

    const u32 nwg = gridDim.x * gridDim.y;
    u32 bid = blockIdx.y * gridDim.x + blockIdx.x;
    bid = (bid & 7) * (nwg >> 3) + (bid >> 3);
    const int tn0 = (bid % gridDim.x) * 64;
    const int tm0 = (bid / gridDim.x) * 128;

    const int r16 = lane & 15, g8 = (lane >> 4) * 8;

    const bf16* gA[4];
    const bf16* gB[2];
    #pragma unroll
    for (int j = 0; j < 4; ++j) {
        int c = (w * 4 + j) * 64 + lane;
        int l = c ^ ((c >> 3) & 7);
        gA[j] = X + (size_t)(tm0 + (c >> 3)) * K + (l & 7) * 8;
    }
    #pragma unroll
    for (int j = 0; j < 2; ++j) {
        int c = (w * 2 + j) * 64 + lane;
        int l = c ^ ((c >> 3) & 7);
        gB[j] = WT + (size_t)(tn0 + (c >> 3)) * K + (l & 7) * 8;
    }
    auto stage = [&](int buf, int kk) {
        #pragma unroll
        for (int j = 0; j < 4; ++j)
            gload_lds16(gA[j] + kk, (char*)&As[buf][0] + (size_t)(w * 4 + j) * 1024);
        #pragma unroll
        for (int j = 0; j < 2; ++j)
            gload_lds16(gB[j] + kk, (char*)&Bs[buf][0] + (size_t)(w * 2 + j) * 1024);
    };

    f32x4 acc[4][2] = {};
    const int nt = K >> 6;
    stage(0, 0);
    __syncthreads();
    for (int t = 0; t < nt; ++t) {
        int buf = t & 1;
        if (t + 1 < nt) stage(buf ^ 1, (t + 1) << 6);
        const char* ab = (const char*)&As[buf][0];
        const char* bb_ = (const char*)&Bs[buf][0];
        #pragma unroll
        for (int k32 = 0; k32 < 2; ++k32) {
            int kcolb = k32 * 64 + g8 * 2;
            bf16x8 xf[4], wf[2];
            #pragma unroll
            for (int m = 0; m < 4; ++m) {
                int row = w1 * 64 + m * 16 + r16;
                int byte = row * 128 + kcolb;
                xf[m] = *(const bf16x8*)(ab + (byte ^ ((row & 7) << 4)));
            }
            #pragma unroll
            for (int n = 0; n < 2; ++n) {
                int row = w0 * 32 + n * 16 + r16;
                int byte = row * 128 + kcolb;
                wf[n] = *(const bf16x8*)(bb_ + (byte ^ ((row & 7) << 4)));
            }
            #pragma unroll
            for (int m = 0; m < 4; ++m)
                #pragma unroll
                for (int n = 0; n < 2; ++n)
                    acc[m][n] = __builtin_amdgcn_mfma_f32_16x16x32_bf16(wf[n], xf[m], acc[m][n], 0, 0, 0);
        }
        __syncthreads();
    }
    epilogue<EPI>(acc, tm0, tn0, w0, w1, lane, N, bias, outb, outf, xres, yin);
}

// ---------------- MFMA attention: block = 1 window (384 thr = 6 waves, one per head). ----------------
__global__ __launch_bounds__(384) void attn_m(const bf16* __restrict__ qkv,
                                              const float* __restrict__ bm,
                                              bf16* __restrict__ out)
{
    __shared__ char Pl[6][8192];    // P[q][kk] bf16, byte = q*128+kk*2 ^ ((q&7)<<4)
    __shared__ char Vt[6][4096];    // V^T[d][kk] bf16, byte = d*128+kk*2 ^ ((d&7)<<4)
    const int w = blockIdx.x;
    const int h = threadIdx.x >> 6, l = threadIdx.x & 63;
    const int w49 = w * 49;
    const int wl = w & 63;
    const int cls = (((wl >> 3) == 7) ? 2 : 0) + (((wl & 7) == 7) ? 1 : 0);
    const int hi8 = (l >> 4) * 8, lo = l & 15;

    {
        const bf16* vbase = qkv + ((size_t)(12 + h) * NTOK + w49) * 32;
        #pragma unroll
        for (int it = 0; it < 4; ++it) {
            int c = it * 64 + l;
            int kk = c >> 2, off = (c & 3) * 8;
            bf16x8 v = {};
            if (c < 196) v = *(const bf16x8*)(vbase + kk * 32 + off);
            #pragma unroll
            for (int j = 0; j < 8; ++j) {
                int d = off + j;
                int byte = (d * 128 + kk * 2) ^ ((d & 7) << 4);
                *(bf16*)(&Vt[h][0] + byte) = ((const bf16*)&v)[j];
            }
        }
    }

    const bf16* qb = qkv + ((size_t)h * NTOK + w49) * 32 + hi8;
    const bf16* kb = qkv + ((size_t)(6 + h) * NTOK + w49) * 32 + hi8;
    bf16x8 af[4], bf_[4];
    #pragma unroll
    for (int mt = 0; mt < 4; ++mt) af[mt] = *(const bf16x8*)(kb + (size_t)(mt * 16 + lo) * 32);
    #pragma unroll
    for (int ntt = 0; ntt < 4; ++ntt) bf_[ntt] = *(const bf16x8*)(qb + (size_t)(ntt * 16 + lo) * 32);
    f32x4 acc[4][4] = {};
    #pragma unroll
    for (int mt = 0; mt < 4; ++mt)
        #pragma unroll
        for (int ntt = 0; ntt < 4; ++ntt)
            acc[mt][ntt] = __builtin_amdgcn_mfma_f32_16x16x32_bf16(af[mt], bf_[ntt], acc[mt][ntt], 0, 0, 0);

    const float scale = 0.17677669529663689f;   // 32^-0.5
    const float* bmb = bm + ((size_t)(cls * 6 + h) << 4) * 256;
    #pragma unroll
    for (int mt = 0; mt < 4; ++mt)
        #pragma unroll
        for (int ntt = 0; ntt < 4; ++ntt) {
            f32x4 bmv = *(const f32x4*)(bmb + (mt * 4 + ntt) * 256 + l * 4);
            #pragma unroll
            for (int r = 0; r < 4; ++r) acc[mt][ntt][r] = acc[mt][ntt][r] * scale + bmv[r];
        }

    float inv[4], mx[4];
    #pragma unroll
    for (int ntt = 0; ntt < 4; ++ntt) {
        float m_ = -1e30f;
        #pragma unroll
        for (int mt = 0; mt < 4; ++mt)
            #pragma unroll
            for (int r = 0; r < 4; ++r) m_ = fmaxf(m_, acc[mt][ntt][r]);
        m_ = fmaxf(m_, __shfl_xor(m_, 16));
        m_ = fmaxf(m_, __shfl_xor(m_, 32));
        mx[ntt] = m_;
    }
    #pragma unroll
    for (int ntt = 0; ntt < 4; ++ntt) {
        float s_ = 0.f;
        #pragma unroll
        for (int mt = 0; mt < 4; ++mt)
            #pragma unroll
            for (int r = 0; r < 4; ++r) {
                float e = __expf(acc[mt][ntt][r] - mx[ntt]);
                acc[mt][ntt][r] = e;
                s_ += e;
            }
        s_ += __shfl_xor(s_, 16);
        s_ += __shfl_xor(s_, 32);
        inv[ntt] = 1.0f / s_;
    }

    #pragma unroll
    for (int mt = 0; mt < 4; ++mt)
        #pragma unroll
        for (int ntt = 0; ntt < 4; ++ntt)
            #pragma unroll
            for (int rp = 0; rp < 4; rp += 2) {
                u32 pk = (u32)f2b(acc[mt][ntt][rp]) | ((u32)f2b(acc[mt][ntt][rp + 1]) << 16);
                int kk = mt * 16 + (l >> 4) * 4 + rp;
                int q  = ntt * 16 + lo;
                int byte = (q * 128 + kk * 2) ^ ((q & 7) << 4);
                *(u32*)(&Pl[h][0] + byte) = pk;
            }

    f32x4 o[4][2] = {};
    #pragma unroll
    for (int ks = 0; ks < 2; ++ks) {
        int kb_ = (ks * 32 + hi8) * 2;
        bf16x8 pa[4], vb[2];
        #pragma unroll
        for (int qt = 0; qt < 4; ++qt) {
            int row = qt * 16 + lo;
            pa[qt] = *(const bf16x8*)(&Pl[h][0] + ((row * 128 + kb_) ^ ((row & 7) << 4)));
        }
        #pragma unroll
        for (int dt = 0; dt < 2; ++dt) {
            int row = dt * 16 + lo;
            vb[dt] = *(const bf16x8*)(&Vt[h][0] + ((row * 128 + kb_) ^ ((row & 7) << 4)));
        }
        #pragma unroll
        for (int qt = 0; qt < 4; ++qt)
            #pragma unroll
            for (int dt = 0; dt < 2; ++dt)
                o[qt][dt] = __builtin_amdgcn_mfma_f32_16x16x32_bf16(pa[qt], vb[dt], o[qt][dt], 0, 0, 0);
    }

    #pragma unroll
    for (int qt = 0; qt < 4; ++qt)
        #pragma unroll
        for (int r = 0; r < 4; ++r) {
            int qrow = (l >> 4) * 4 + r;
            float iv = __shfl(inv[qt], qrow);
            int q = qt * 16 + qrow;
            if (q < 49) {
                size_t ob = (size_t)(w49 + q) * CC + h * 32 + lo;
                out[ob]      = __float2bfloat16(o[qt][0][r] * iv);
                out[ob + 16] = __float2bfloat16(o[qt][1][r] * iv);
            }
        }
}

// ---------------- launch ----------------
extern "C" void kernel_launch(void* const* d_in, const int* in_sizes, int n_in,
                              void* d_out, int out_size, void* d_ws, size_t ws_size,
                              hipStream_t stream) {
    const float* x      = (const float*)d_in[0];
    const float* n1g    = (const float*)d_in[1];
    const float* n1b    = (const float*)d_in[2];
    const float* qkv_w  = (const float*)d_in[3];
    const float* qkv_b  = (const float*)d_in[4];
    const float* proj_w = (const float*)d_in[5];
    const float* proj_b = (const float*)d_in[6];
    const float* btab   = (const float*)d_in[7];
    const float* n2g    = (const float*)d_in[8];
    const float* n2b    = (const float*)d_in[9];
    const float* fc1_w  = (const float*)d_in[10];
    const float* fc1_b  = (const float*)d_in[11];
    const float* fc2_w  = (const float*)d_in[12];
    const float* fc2_b  = (const float*)d_in[13];

    char* ws = (char*)d_ws;
    //  xw   [0, 38535168)            bf16 [100352][192]  (LN1 out; reused as LN2 out m)
    //  qkv  [38535168, 154140672)    bf16 head-planar [3][6][NTOK][32]
    //        (MLP phase: hid bf16 [100352][768] reuses [38535168, 192675840))
    //  att  [154140672, 192675840)   bf16 [100352][192]
    //  wt   [192675840, 193560576)   transposed bf16 weights
    //  bm   [193560576, 193953792)   biasmask f32 [4][6][16][256]
    //  y (fp32) lives in d_out.
    const size_t XW_OFF  = 0;
    const size_t QKV_OFF = 38535168;
    const size_t ATT_OFF = 154140672;
    const size_t WT_OFF  = 192675840;
    const size_t BM_OFF  = 193560576;
    if (ws_size < 193953792ull) return;   // diagnostic: zeros signature (absmax ~5.59)

    bf16* xw   = (bf16*)(ws + XW_OFF);
    bf16* mbuf = (bf16*)(ws + XW_OFF);
    bf16* qkvb = (bf16*)(ws + QKV_OFF);
    bf16* attb = (bf16*)(ws + ATT_OFF);
    bf16* hidb = (bf16*)(ws + QKV_OFF);
    float* yf  = (float*)d_out;
    bf16* wt   = (bf16*)(ws + WT_OFF);
    float* bmt = (float*)(ws + BM_OFF);
    bf16* qkv_wT  = wt;                       // [576][192]
    bf16* proj_wT = wt + 110592;              // [192][192]
    bf16* fc1_wT  = wt + 147456;              // [768][192]
    bf16* fc2_wT  = wt + 294912;              // [192][768]

    transpose_k<<<dim3(432), 256, 0, stream>>>(qkv_w, qkv_wT, 192, 576);
    transpose_k<<<dim3(144), 256, 0, stream>>>(proj_w, proj_wT, 192, 192);
    transpose_k<<<dim3(576), 256, 0, stream>>>(fc1_w, fc1_wT, 192, 768);
    transpose_k<<<dim3(576), 256, 0, stream>>>(fc2_w, fc2_wT, 768, 192);
    bm_k<<<dim3(384), 256, 0, stream>>>(btab, bmt);

    ln_k<true><<<NTOK / 4, 256, 0, stream>>>(x, n1g, n1b, xw);

    gemm_ss<4><<<dim3(9, 784), 256, 0, stream>>>(
        xw, qkv_wT, qkv_b, 192, 576, qkvb, nullptr, nullptr, nullptr);
    attn_m<<<dim3(2048), 384, 0, stream>>>(qkvb, bmt, attb);
    gemm_ss<1><<<dim3(3, 784), 256, 0, stream>>>(
        attb, proj_wT, proj_b, 192, 192, nullptr, yf, x, nullptr);

    ln_k<false><<<NTOK / 4, 256, 0, stream>>>(yf, n2g, n2b, mbuf);

    gemm_ss<2><<<dim3(12, 784), 256, 0, stream>>>(
        mbuf, fc1_wT, fc1_b, 192, 768, hidb, nullptr, nullptr, nullptr);
    gemm_db<3><<<dim3(3, 784), 256, 0, stream>>>(
        hidb, fc2_wT, fc2_b, 768, 192, nullptr, yf, nullptr, yf);
}